// Round 2
// baseline (18203.932 us; speedup 1.0000x reference)
//
#include <hip/hip_runtime.h>
#include <hip/hip_bf16.h>

// Model dims
#define BB 64
#define TT 512
#define DD 512
#define EE 6
#define PP 96
#define NHH 4
#define HDD 128
#define FFF 2048

typedef short bf16x8 __attribute__((ext_vector_type(8)));
typedef float f32x4 __attribute__((ext_vector_type(4)));

__device__ __forceinline__ float bf2f(unsigned short u) {
    unsigned int x = ((unsigned int)u) << 16;
    return __uint_as_float(x);
}
__device__ __forceinline__ unsigned short f2bf(float f) {
    __hip_bfloat16 h = __float2bfloat16(f);
    return *reinterpret_cast<unsigned short*>(&h);
}

// ---------------------------------------------------------------------------
// Generic MFMA GEMM:  C[m][n] = alpha * sum_k A[m][k] * W[n][k]  (+bias[n])
// 128x128 tile, BK=32, 256 threads (4 waves, each a 64x64 quadrant of
// 4x4 mfma_f32_16x16x32_bf16). TRANSW stages W[k*ldw+n] (V^T for P·V).
// Batched via blockIdx.z -> (b = z/Hdiv, h = z%Hdiv) offsets.
// ---------------------------------------------------------------------------
template<bool TRANSW, bool BIAS, bool RELU, bool OUTBF16>
__global__ __launch_bounds__(256) void gemm_bt(
    const unsigned short* __restrict__ A, int lda, long long aB, long long aH,
    const unsigned short* __restrict__ W, int ldw, long long wB, long long wH,
    const float* __restrict__ bias,
    void* __restrict__ Cv, int ldc, long long cB, long long cH,
    int K, int Hdiv, float alpha)
{
    __shared__ unsigned short As[128 * 40];
    __shared__ unsigned short Ws[128 * 40];
    int t = threadIdx.x;
    int z = blockIdx.z;
    int zb = z / Hdiv, zh = z - zb * Hdiv;
    long long aOff = (long long)zb * aB + (long long)zh * aH;
    long long wOff = (long long)zb * wB + (long long)zh * wH;
    long long cOff = (long long)zb * cB + (long long)zh * cH;
    int m0 = blockIdx.x * 128, n0 = blockIdx.y * 128;

    int arow = t >> 1, acol = (t & 1) * 16;
    const unsigned short* Ag = A + aOff + (long long)(m0 + arow) * lda + acol;
    const unsigned short* WgN = W + wOff + (long long)(n0 + arow) * ldw + acol;
    int wk = t >> 3, wn = (t & 7) * 16;
    const unsigned short* WgT = W + wOff + n0 + wn;

    int wave = t >> 6, lane = t & 63;
    int wm = (wave & 1) * 64, wn2 = (wave >> 1) * 64;
    int lrow = lane & 15, quad = lane >> 4;

    f32x4 acc[4][4];
    #pragma unroll
    for (int i = 0; i < 4; i++)
        #pragma unroll
        for (int j = 0; j < 4; j++)
            acc[i][j] = (f32x4){0.f, 0.f, 0.f, 0.f};

    for (int k0 = 0; k0 < K; k0 += 32) {
        __syncthreads();
        {
            uint4 a0 = *(const uint4*)(Ag + k0);
            uint4 a1 = *(const uint4*)(Ag + k0 + 8);
            *(uint4*)&As[arow * 40 + acol] = a0;
            *(uint4*)&As[arow * 40 + acol + 8] = a1;
            if (!TRANSW) {
                uint4 w0 = *(const uint4*)(WgN + k0);
                uint4 w1 = *(const uint4*)(WgN + k0 + 8);
                *(uint4*)&Ws[arow * 40 + acol] = w0;
                *(uint4*)&Ws[arow * 40 + acol + 8] = w1;
            } else {
                const unsigned short* p = WgT + (long long)(k0 + wk) * ldw;
                uint4 w0 = *(const uint4*)(p);
                uint4 w1 = *(const uint4*)(p + 8);
                const unsigned short* s0 = (const unsigned short*)&w0;
                const unsigned short* s1 = (const unsigned short*)&w1;
                #pragma unroll
                for (int j = 0; j < 8; j++) Ws[(wn + j) * 40 + wk] = s0[j];
                #pragma unroll
                for (int j = 0; j < 8; j++) Ws[(wn + 8 + j) * 40 + wk] = s1[j];
            }
        }
        __syncthreads();
        bf16x8 af[4], bf[4];
        #pragma unroll
        for (int i = 0; i < 4; i++)
            af[i] = *(const bf16x8*)&As[(wm + i * 16 + lrow) * 40 + quad * 8];
        #pragma unroll
        for (int j = 0; j < 4; j++)
            bf[j] = *(const bf16x8*)&Ws[(wn2 + j * 16 + lrow) * 40 + quad * 8];
        #pragma unroll
        for (int i = 0; i < 4; i++)
            #pragma unroll
            for (int j = 0; j < 4; j++)
                acc[i][j] = __builtin_amdgcn_mfma_f32_16x16x32_bf16(af[i], bf[j], acc[i][j], 0, 0, 0);
    }

    #pragma unroll
    for (int i = 0; i < 4; i++) {
        #pragma unroll
        for (int j = 0; j < 4; j++) {
            #pragma unroll
            for (int r = 0; r < 4; r++) {
                int row = m0 + wm + i * 16 + quad * 4 + r;
                int col = n0 + wn2 + j * 16 + lrow;
                float v = acc[i][j][r] * alpha;
                if (BIAS) v += bias[col];
                if (RELU) v = fmaxf(v, 0.f);
                long long idx = cOff + (long long)row * ldc + col;
                if (OUTBF16) ((unsigned short*)Cv)[idx] = f2bf(v);
                else         ((float*)Cv)[idx] = v;
            }
        }
    }
}

// ---------------------------------------------------------------------------
__global__ void cvt_k(const float* __restrict__ in, unsigned short* __restrict__ out, int n)
{
    int i = blockIdx.x * 256 + threadIdx.x;
    int stride = gridDim.x * 256;
    for (; i < n; i += stride) out[i] = f2bf(in[i]);
}

// ---------------------------------------------------------------------------
// GARCH: per-batch variance + 511-step scalar recurrence. 1 block, lane = batch.
// ---------------------------------------------------------------------------
__global__ __launch_bounds__(64) void garch_k(
    const float* __restrict__ xe, const float* __restrict__ omega,
    const float* __restrict__ alpha, const float* __restrict__ beta,
    float* __restrict__ vol)
{
    int b = threadIdx.x;
    float sm = 0.f, sq = 0.f;
    for (int t2 = 0; t2 < TT; t2++) {
        float r = xe[((long long)b * TT + t2) * EE + 5];
        sm += r; sq += r * r;
    }
    float mean = sm / 512.f;
    float var = (sq - 512.f * mean * mean) / 511.f;
    float h = var + 1e-6f;
    float om = log1pf(expf(omega[0]));
    float al = 0.2f / (1.f + expf(-alpha[0]));
    float be = 0.8f / (1.f + expf(-beta[0]));
    for (int t2 = 0; t2 < TT - 1; t2++) {
        float r = xe[((long long)b * TT + t2) * EE + 5];
        h = om + al * r * r + be * h;
    }
    vol[b] = sqrtf(h);
}

// ---------------------------------------------------------------------------
// Persistent LSTM v2 — fence-free coherence.
//
// Round-0 post-mortem: __threadfence() (agent acq_rel) on gfx950 does a full
// L2 writeback + L1/L2 invalidate each step -> w_hh refetched cold every
// step, all h loads ~700cy far misses at 1 wave/SIMD occupancy -> 28us/step.
//
// v2: per-access coherence instead of cache maintenance.
//   - h stores:  __hip_atomic_store(RELAXED, AGENT)  (write-through to MALL)
//   - h loads:   __hip_atomic_load(RELAXED, AGENT)   (bypass stale L1/L2)
//   - NO threadfence anywhere -> w_hh / w_ih / xe stay cached across steps.
//   - barrier arrival preceded by inline s_waitcnt vmcnt(0) (stores landed);
//     all barrier atomics RELAXED; ordering vs spin via __syncthreads().
//
// Geometry: 256 blocks x 512 threads (8 waves). wave = dl*4+kq:
//   dl = wave>>2 : which of the block's 2 dims (d = 2*blk + dl)
//   kq = wave&3  : K quarter (128 k's) -> 2+ waves/SIMD, latency hiding.
// Per thread: 128 coherent h loads (ping-pong chunks of 16, static indices)
// + 512 FMAs into 4 gate accumulators. LDS reduce across kq, finalize in
// kq==0 waves (c-state in registers), h write-through, barrier.
// Deadlock-safe by capacity: 256 blocks <= 256 CUs @ 1 block/CU.
// ---------------------------------------------------------------------------
__global__ __launch_bounds__(512, 2) void lstm_persist2_k(
    const float* __restrict__ xe, const float* __restrict__ w_hh,
    const float* __restrict__ w_ih, const float* __restrict__ b_ih,
    const float* __restrict__ b_hh,
    float* __restrict__ h0, float* __restrict__ h1,
    float* __restrict__ xT,
    unsigned* __restrict__ root, unsigned* __restrict__ grp)
{
    int blk = blockIdx.x;
    int tid = threadIdx.x;
    int wave = tid >> 6, lane = tid & 63;
    int dl = wave >> 2;      // 0..1
    int kq = wave & 3;       // 0..3
    int d = blk * 2 + dl;    // 0..511

    __shared__ float part[8][4][64];

    const float* wrow = w_hh + (long long)d * 512 + kq * 128;

    bool fin = (kq == 0);
    float wi[4][6], bs[4];
    if (fin) {
        #pragma unroll
        for (int g = 0; g < 4; g++) {
            int row = g * 512 + d;
            #pragma unroll
            for (int e = 0; e < 6; e++) wi[g][e] = w_ih[row * 6 + e];
            bs[g] = b_ih[row] + b_hh[row];
        }
    }
    float c = 0.f;

    for (int t = 0; t < TT; t++) {
        const float* hin  = (t & 1) ? h1 : h0;
        float*       hout = (t & 1) ? h0 : h1;
        const float* hp = hin + kq * (128 * 64) + lane;

        // Prefetch xe(t) for finalize waves (independent of h -> hides
        // under the k-loop).
        float x0 = 0.f, x1 = 0.f, x2 = 0.f, x3 = 0.f, x4 = 0.f, x5 = 0.f;
        if (fin) {
            const float* xr = xe + ((long long)lane * TT + t) * EE;
            x0 = xr[0]; x1 = xr[1]; x2 = xr[2];
            x3 = xr[3]; x4 = xr[4]; x5 = xr[5];
        }

        float a0 = 0.f, a1 = 0.f, a2 = 0.f, a3 = 0.f;
        float hA[16], hB[16];
        #pragma unroll
        for (int j = 0; j < 16; j++)
            hA[j] = __hip_atomic_load(&hp[j * 64], __ATOMIC_RELAXED,
                                      __HIP_MEMORY_SCOPE_AGENT);
        #pragma unroll
        for (int cc = 0; cc < 8; cc++) {
            const float* hcur = (cc & 1) ? hB : hA;  // static after unroll
            float*       hnxt = (cc & 1) ? hA : hB;
            if (cc < 7) {
                #pragma unroll
                for (int j = 0; j < 16; j++)
                    hnxt[j] = __hip_atomic_load(&hp[((cc + 1) * 16 + j) * 64],
                                                __ATOMIC_RELAXED,
                                                __HIP_MEMORY_SCOPE_AGENT);
            }
            #pragma unroll
            for (int j = 0; j < 16; j++) {
                int k = cc * 16 + j;
                float hv = hcur[j];
                a0 += hv * wrow[k];
                a1 += hv * wrow[262144 + k];
                a2 += hv * wrow[524288 + k];
                a3 += hv * wrow[786432 + k];
            }
        }

        part[wave][0][lane] = a0; part[wave][1][lane] = a1;
        part[wave][2][lane] = a2; part[wave][3][lane] = a3;
        __syncthreads();   // sync1: partials visible

        if (fin) {
            int w0 = dl * 4;
            float s0 = part[w0][0][lane] + part[w0 + 1][0][lane]
                     + part[w0 + 2][0][lane] + part[w0 + 3][0][lane];
            float s1 = part[w0][1][lane] + part[w0 + 1][1][lane]
                     + part[w0 + 2][1][lane] + part[w0 + 3][1][lane];
            float s2 = part[w0][2][lane] + part[w0 + 1][2][lane]
                     + part[w0 + 2][2][lane] + part[w0 + 3][2][lane];
            float s3 = part[w0][3][lane] + part[w0 + 1][3][lane]
                     + part[w0 + 2][3][lane] + part[w0 + 3][3][lane];
            float pi = s0 + x0*wi[0][0] + x1*wi[0][1] + x2*wi[0][2]
                          + x3*wi[0][3] + x4*wi[0][4] + x5*wi[0][5] + bs[0];
            float pf = s1 + x0*wi[1][0] + x1*wi[1][1] + x2*wi[1][2]
                          + x3*wi[1][3] + x4*wi[1][4] + x5*wi[1][5] + bs[1];
            float pg = s2 + x0*wi[2][0] + x1*wi[2][1] + x2*wi[2][2]
                          + x3*wi[2][3] + x4*wi[2][4] + x5*wi[2][5] + bs[2];
            float po = s3 + x0*wi[3][0] + x1*wi[3][1] + x2*wi[3][2]
                          + x3*wi[3][3] + x4*wi[3][4] + x5*wi[3][5] + bs[3];
            float ig = 1.f / (1.f + __expf(-pi));
            float fg = 1.f / (1.f + __expf(-pf));
            float gg = tanhf(pg);
            float og = 1.f / (1.f + __expf(-po));
            c = fg * c + ig * gg;
            float hn = og * tanhf(c);
            __hip_atomic_store(&hout[d * 64 + lane], hn, __ATOMIC_RELAXED,
                               __HIP_MEMORY_SCOPE_AGENT);
            xT[((long long)t * 512 + d) * 64 + lane] = hn;
            // h stores must be at the coherence point before arrival.
            asm volatile("s_waitcnt vmcnt(0)" ::: "memory");
        }
        __syncthreads();   // sync2: both fin waves' stores landed

        if (t < TT - 1) {
            if (tid == 0) {
                int g = blk >> 4;
                unsigned p = __hip_atomic_fetch_add(&grp[g * 512 + t], 1u,
                                 __ATOMIC_RELAXED, __HIP_MEMORY_SCOPE_AGENT);
                if (p == 15u) {
                    __hip_atomic_fetch_add(&root[t], 1u,
                        __ATOMIC_RELAXED, __HIP_MEMORY_SCOPE_AGENT);
                }
                unsigned tries = 0;
                while (__hip_atomic_load(&root[t], __ATOMIC_RELAXED,
                                         __HIP_MEMORY_SCOPE_AGENT) < 16u) {
                    __builtin_amdgcn_s_sleep(1);
                    if (++tries > 100000000u) break;   // fail loudly, never wedge
                }
            }
            __syncthreads();   // sync3: release whole block into step t+1
        }
    }
}

// ---------------------------------------------------------------------------
// Transpose xT[t][d][b] -> XB[b][t][d] bf16
// ---------------------------------------------------------------------------
__global__ __launch_bounds__(256) void transpose_k(
    const float* __restrict__ xT, unsigned short* __restrict__ XB_)
{
    __shared__ float tile[64][65];
    int dc = blockIdx.x, t = blockIdx.y;
    int tid = threadIdx.x;
    int bcol = tid & 63, grp = tid >> 6;
    #pragma unroll
    for (int j = 0; j < 16; j++) {
        int i = grp * 16 + j;
        tile[i][bcol] = xT[((long long)t * 512 + dc * 64 + i) * 64 + bcol];
    }
    __syncthreads();
    #pragma unroll
    for (int j = 0; j < 16; j++) {
        int brow = grp * 16 + j;
        float v = tile[bcol][brow];
        long long idx = ((long long)brow * TT + t) * DD + dc * 64 + bcol;
        XB_[idx] = f2bf(v);
    }
}

// ---------------------------------------------------------------------------
// Softmax over last dim (512), in-place on bf16 scores. One wave per row.
// ---------------------------------------------------------------------------
__global__ __launch_bounds__(256) void softmax_k(unsigned short* __restrict__ S)
{
    long long row = (long long)blockIdx.x * 4 + (threadIdx.x >> 6);
    int lane = threadIdx.x & 63;
    unsigned short* p = S + row * 512 + lane * 8;
    uint4 raw = *(const uint4*)p;
    unsigned short* u = (unsigned short*)&raw;
    float v[8];
    float m = -1e30f;
    #pragma unroll
    for (int j = 0; j < 8; j++) { v[j] = bf2f(u[j]); m = fmaxf(m, v[j]); }
    #pragma unroll
    for (int off = 1; off < 64; off <<= 1) m = fmaxf(m, __shfl_xor(m, off));
    float s = 0.f;
    #pragma unroll
    for (int j = 0; j < 8; j++) { v[j] = __expf(v[j] - m); s += v[j]; }
    #pragma unroll
    for (int off = 1; off < 64; off <<= 1) s += __shfl_xor(s, off);
    float inv = 1.f / s;
    unsigned int pk[4];
    #pragma unroll
    for (int j = 0; j < 4; j++)
        pk[j] = (unsigned int)f2bf(v[2 * j] * inv) | ((unsigned int)f2bf(v[2 * j + 1] * inv) << 16);
    *(uint4*)p = make_uint4(pk[0], pk[1], pk[2], pk[3]);
}

// ---------------------------------------------------------------------------
// Residual + LayerNorm: XB = LN(XB + Y)*g + b  (bf16 residual stream).
// ---------------------------------------------------------------------------
__global__ __launch_bounds__(256) void ln_k(
    unsigned short* XB_, const float* __restrict__ Y_,
    const float* __restrict__ g, const float* __restrict__ b2)
{
    long long row = (long long)blockIdx.x * 4 + (threadIdx.x >> 6);
    int lane = threadIdx.x & 63;
    long long base = row * 512 + lane * 8;
    float s[8];
    {
        uint4 xr = *(const uint4*)&XB_[base];
        const unsigned short* xu = (const unsigned short*)&xr;
        float4 y0 = *(const float4*)&Y_[base];
        float4 y1 = *(const float4*)&Y_[base + 4];
        s[0] = bf2f(xu[0]) + y0.x; s[1] = bf2f(xu[1]) + y0.y;
        s[2] = bf2f(xu[2]) + y0.z; s[3] = bf2f(xu[3]) + y0.w;
        s[4] = bf2f(xu[4]) + y1.x; s[5] = bf2f(xu[5]) + y1.y;
        s[6] = bf2f(xu[6]) + y1.z; s[7] = bf2f(xu[7]) + y1.w;
    }
    float sm = 0.f, sq = 0.f;
    #pragma unroll
    for (int j = 0; j < 8; j++) { sm += s[j]; sq += s[j] * s[j]; }
    #pragma unroll
    for (int off = 1; off < 64; off <<= 1) {
        sm += __shfl_xor(sm, off);
        sq += __shfl_xor(sq, off);
    }
    float mean = sm * (1.f / 512.f);
    float var = sq * (1.f / 512.f) - mean * mean;
    float rstd = rsqrtf(var + 1e-5f);
    int col = lane * 8;
    float o[8];
    #pragma unroll
    for (int j = 0; j < 8; j++) o[j] = (s[j] - mean) * rstd * g[col + j] + b2[col + j];
    unsigned int pk[4];
    #pragma unroll
    for (int j = 0; j < 4; j++)
        pk[j] = (unsigned int)f2bf(o[2 * j]) | ((unsigned int)f2bf(o[2 * j + 1]) << 16);
    *(uint4*)&XB_[base] = make_uint4(pk[0], pk[1], pk[2], pk[3]);
}

// ---------------------------------------------------------------------------
// Heads: garch_base + gate * ai_residual. One block per batch.
// ---------------------------------------------------------------------------
__global__ __launch_bounds__(128) void head_k(
    const unsigned short* __restrict__ XB_, const float* __restrict__ xe,
    const float* __restrict__ vol,
    const float* __restrict__ rh_w, const float* __restrict__ rh_b,
    const float* __restrict__ g1_w, const float* __restrict__ g1_b,
    const float* __restrict__ g2_w, const float* __restrict__ g2_b,
    const float* __restrict__ gp_w, const float* __restrict__ gp_b,
    float* __restrict__ out)
{
    int b = blockIdx.x, t = threadIdx.x;
    __shared__ float xl[512];
    __shared__ float hid[256];
    for (int j = t; j < 512; j += 128)
        xl[j] = bf2f(XB_[((long long)b * TT + (TT - 1)) * DD + j]);
    float gin[7];
    #pragma unroll
    for (int e = 0; e < 6; e++) gin[e] = xe[((long long)b * TT + (TT - 1)) * EE + e];
    gin[6] = vol[b];
    for (int j = t; j < 256; j += 128) {
        float s = g1_b[j];
        #pragma unroll
        for (int e = 0; e < 7; e++) s += g1_w[j * 7 + e] * gin[e];
        hid[j] = fmaxf(s, 0.f);
    }
    __syncthreads();
    for (int p = t; p < 96; p += 128) {
        float ai = rh_b[p];
        for (int j = 0; j < 512; j++) ai += xl[j] * rh_w[p * 512 + j];
        float gs = g2_b[p];
        for (int j = 0; j < 256; j++) gs += hid[j] * g2_w[p * 256 + j];
        float gate = 1.f / (1.f + expf(-gs));
        out[b * PP + p] = vol[b] * gp_w[p] + gp_b[p] + gate * ai;
    }
}

// ---------------------------------------------------------------------------
// Launch.  Workspace layout (bytes, total ~147.2 MB):
//   XB   bf16 residual  @ 0           (33554432)
//   Y    fp32 branch    @ 33554432    (67108864)   [aliases LSTM xT]
//   CH   chunk region   @ 100663296   (33554432)
//        QKVc @ +0 | SCc @ +12582912 | CTXc @ +29360128 ; HIDc @ +0 [FFN]
//   WB   bf16 weights   @ 134217728   (12582912)
//   HT0/HT1             @ 146800640   (2 x 131072)
//   BAR  barrier slots  @ 147062784   (34816: root 512 u32, grp 16x512 u32)
//   VOL                 @ 147193856   (256)
// ---------------------------------------------------------------------------
extern "C" void kernel_launch(void* const* d_in, const int* in_sizes, int n_in,
                              void* d_out, int out_size, void* d_ws, size_t ws_size,
                              hipStream_t stream)
{
    const float* x_enc      = (const float*)d_in[0];
    const float* omega      = (const float*)d_in[4];
    const float* alpha      = (const float*)d_in[5];
    const float* beta       = (const float*)d_in[6];
    const float* gp_w       = (const float*)d_in[7];
    const float* gp_b       = (const float*)d_in[8];
    const float* w_ih       = (const float*)d_in[9];
    const float* w_hh       = (const float*)d_in[10];
    const float* b_ih       = (const float*)d_in[11];
    const float* b_hh       = (const float*)d_in[12];
    const float* attn_in_w  = (const float*)d_in[13];
    const float* attn_in_b  = (const float*)d_in[14];
    const float* attn_out_w = (const float*)d_in[15];
    const float* attn_out_b = (const float*)d_in[16];
    const float* ln1_g      = (const float*)d_in[17];
    const float* ln1_b      = (const float*)d_in[18];
    const float* ffn_w1     = (const float*)d_in[19];
    const float* ffn_b1     = (const float*)d_in[20];
    const float* ffn_w2     = (const float*)d_in[21];
    const float* ffn_b2     = (const float*)d_in[22];
    const float* ln2_g      = (const float*)d_in[23];
    const float* ln2_b      = (const float*)d_in[24];
    const float* rh_w       = (const float*)d_in[25];
    const float* rh_b       = (const float*)d_in[26];
    const float* g1_w       = (const float*)d_in[27];
    const float* g1_b       = (const float*)d_in[28];
    const float* g2_w       = (const float*)d_in[29];
    const float* g2_b       = (const float*)d_in[30];

    char* ws = (char*)d_ws;
    unsigned short* XB   = (unsigned short*)(ws + 0);
    float*          Y    = (float*)(ws + 33554432LL);
    float*          XT   = Y;
    unsigned short* QKVc = (unsigned short*)(ws + 100663296LL);
    unsigned short* SCc  = (unsigned short*)(ws + 113246208LL);
    unsigned short* CTXc = (unsigned short*)(ws + 130023424LL);
    unsigned short* HIDc = (unsigned short*)(ws + 100663296LL);
    unsigned short* WATI = (unsigned short*)(ws + 134217728LL);
    unsigned short* WATO = WATI + 1572864;
    unsigned short* WF1  = WATI + 2097152;
    unsigned short* WF2  = WATI + 4194304;
    float*          HT0  = (float*)(ws + 146800640LL);
    float*          HT1  = (float*)(ws + 146931712LL);
    unsigned*       ROOT = (unsigned*)(ws + 147062784LL);
    unsigned*       GRP  = ROOT + 512;
    float*          VOL  = (float*)(ws + 147193856LL);

    hipMemsetAsync(HT0, 0, 131072, stream);
    hipMemsetAsync(ROOT, 0, 34816, stream);

    cvt_k<<<2048, 256, 0, stream>>>(attn_in_w,  WATI, 1572864);
    cvt_k<<<1024, 256, 0, stream>>>(attn_out_w, WATO, 524288);
    cvt_k<<<2048, 256, 0, stream>>>(ffn_w1,     WF1,  2097152);
    cvt_k<<<2048, 256, 0, stream>>>(ffn_w2,     WF2,  2097152);

    garch_k<<<1, 64, 0, stream>>>(x_enc, omega, alpha, beta, VOL);

    // Persistent LSTM v2: one launch, fence-free coherence.
    lstm_persist2_k<<<256, 512, 0, stream>>>(x_enc, w_hh, w_ih, b_ih, b_hh,
                                             HT0, HT1, XT, ROOT, GRP);

    transpose_k<<<dim3(8, 512, 1), 256, 0, stream>>>(XT, XB);

    for (int l = 0; l < 2; l++) {
        // Attention, chunked over batches: 8 chunks x 8 batches (4096 rows)
        for (int c = 0; c < 8; c++) {
            long long rowOff = (long long)c * 8 * 512;
            gemm_bt<false, true, false, true><<<dim3(32, 12, 1), 256, 0, stream>>>(
                XB + rowOff * 512, 512, 0, 0,
                WATI + l * 786432, 512, 0, 0, attn_in_b + l * 1536,
                QKVc, 1536, 0, 0, 512, 1, 1.0f);
            gemm_bt<false, false, false, true><<<dim3(4, 4, 32), 256, 0, stream>>>(
                QKVc, 1536, 786432LL, 128LL, QKVc + 512, 1536, 786432LL, 128LL, nullptr,
                SCc, 512, 1048576LL, 262144LL, 128, 4, 0.088388347648318447f);
            softmax_k<<<4096, 256, 0, stream>>>(SCc);
            gemm_bt<true, false, false, true><<<dim3(4, 1, 32), 256, 0, stream>>>(
                SCc, 512, 1048576LL, 262144LL, QKVc + 1024, 1536, 786432LL, 128LL, nullptr,
                CTXc, 512, 262144LL, 128LL, 512, 4, 1.0f);
            gemm_bt<false, true, false, false><<<dim3(32, 4, 1), 256, 0, stream>>>(
                CTXc, 512, 0, 0, WATO + l * 262144, 512, 0, 0, attn_out_b + l * 512,
                Y + rowOff * 512, 512, 0, 0, 512, 1, 1.0f);
        }
        ln_k<<<8192, 256, 0, stream>>>(XB, Y, ln1_g + l * 512, ln1_b + l * 512);

        // FFN, chunked over rows: 4 chunks x 8192 rows
        for (int mc = 0; mc < 4; mc++) {
            long long rowOff = (long long)mc * 8192;
            gemm_bt<false, true, true, true><<<dim3(64, 16, 1), 256, 0, stream>>>(
                XB + rowOff * 512, 512, 0, 0,
                WF1 + l * 1048576, 512, 0, 0, ffn_b1 + l * 2048,
                HIDc, 2048, 0, 0, 512, 1, 1.0f);
            gemm_bt<false, true, false, false><<<dim3(64, 4, 1), 256, 0, stream>>>(
                HIDc, 2048, 0, 0, WF2 + l * 1048576, 2048, 0, 0, ffn_b2 + l * 512,
                Y + rowOff * 512, 512, 0, 0, 2048, 1, 1.0f);
        }
        ln_k<<<8192, 256, 0, stream>>>(XB, Y, ln2_g + l * 512, ln2_b + l * 512);
    }

    head_k<<<64, 128, 0, stream>>>(XB, x_enc, VOL, rh_w, rh_b,
                                   g1_w, g1_b, g2_w, g2_b, gp_w, gp_b,
                                   (float*)d_out);
}

// Round 3
// 9063.293 us; speedup vs baseline: 2.0085x; 2.0085x over previous
//
#include <hip/hip_runtime.h>
#include <hip/hip_bf16.h>

// Model dims
#define BB 64
#define TT 512
#define DD 512
#define EE 6
#define PP 96
#define NHH 4
#define HDD 128
#define FFF 2048

typedef short bf16x8 __attribute__((ext_vector_type(8)));
typedef float f32x4 __attribute__((ext_vector_type(4)));

__device__ __forceinline__ float bf2f(unsigned short u) {
    unsigned int x = ((unsigned int)u) << 16;
    return __uint_as_float(x);
}
__device__ __forceinline__ unsigned short f2bf(float f) {
    __hip_bfloat16 h = __float2bfloat16(f);
    return *reinterpret_cast<unsigned short*>(&h);
}

// ---------------------------------------------------------------------------
// Generic MFMA GEMM:  C[m][n] = alpha * sum_k A[m][k] * W[n][k]  (+bias[n])
// 128x128 tile, BK=32, 256 threads (4 waves, each a 64x64 quadrant of
// 4x4 mfma_f32_16x16x32_bf16). TRANSW stages W[k*ldw+n] (V^T for P·V).
// Batched via blockIdx.z -> (b = z/Hdiv, h = z%Hdiv) offsets.
// ---------------------------------------------------------------------------
template<bool TRANSW, bool BIAS, bool RELU, bool OUTBF16>
__global__ __launch_bounds__(256) void gemm_bt(
    const unsigned short* __restrict__ A, int lda, long long aB, long long aH,
    const unsigned short* __restrict__ W, int ldw, long long wB, long long wH,
    const float* __restrict__ bias,
    void* __restrict__ Cv, int ldc, long long cB, long long cH,
    int K, int Hdiv, float alpha)
{
    __shared__ unsigned short As[128 * 40];
    __shared__ unsigned short Ws[128 * 40];
    int t = threadIdx.x;
    int z = blockIdx.z;
    int zb = z / Hdiv, zh = z - zb * Hdiv;
    long long aOff = (long long)zb * aB + (long long)zh * aH;
    long long wOff = (long long)zb * wB + (long long)zh * wH;
    long long cOff = (long long)zb * cB + (long long)zh * cH;
    int m0 = blockIdx.x * 128, n0 = blockIdx.y * 128;

    int arow = t >> 1, acol = (t & 1) * 16;
    const unsigned short* Ag = A + aOff + (long long)(m0 + arow) * lda + acol;
    const unsigned short* WgN = W + wOff + (long long)(n0 + arow) * ldw + acol;
    int wk = t >> 3, wn = (t & 7) * 16;
    const unsigned short* WgT = W + wOff + n0 + wn;

    int wave = t >> 6, lane = t & 63;
    int wm = (wave & 1) * 64, wn2 = (wave >> 1) * 64;
    int lrow = lane & 15, quad = lane >> 4;

    f32x4 acc[4][4];
    #pragma unroll
    for (int i = 0; i < 4; i++)
        #pragma unroll
        for (int j = 0; j < 4; j++)
            acc[i][j] = (f32x4){0.f, 0.f, 0.f, 0.f};

    for (int k0 = 0; k0 < K; k0 += 32) {
        __syncthreads();
        {
            uint4 a0 = *(const uint4*)(Ag + k0);
            uint4 a1 = *(const uint4*)(Ag + k0 + 8);
            *(uint4*)&As[arow * 40 + acol] = a0;
            *(uint4*)&As[arow * 40 + acol + 8] = a1;
            if (!TRANSW) {
                uint4 w0 = *(const uint4*)(WgN + k0);
                uint4 w1 = *(const uint4*)(WgN + k0 + 8);
                *(uint4*)&Ws[arow * 40 + acol] = w0;
                *(uint4*)&Ws[arow * 40 + acol + 8] = w1;
            } else {
                const unsigned short* p = WgT + (long long)(k0 + wk) * ldw;
                uint4 w0 = *(const uint4*)(p);
                uint4 w1 = *(const uint4*)(p + 8);
                const unsigned short* s0 = (const unsigned short*)&w0;
                const unsigned short* s1 = (const unsigned short*)&w1;
                #pragma unroll
                for (int j = 0; j < 8; j++) Ws[(wn + j) * 40 + wk] = s0[j];
                #pragma unroll
                for (int j = 0; j < 8; j++) Ws[(wn + 8 + j) * 40 + wk] = s1[j];
            }
        }
        __syncthreads();
        bf16x8 af[4], bf[4];
        #pragma unroll
        for (int i = 0; i < 4; i++)
            af[i] = *(const bf16x8*)&As[(wm + i * 16 + lrow) * 40 + quad * 8];
        #pragma unroll
        for (int j = 0; j < 4; j++)
            bf[j] = *(const bf16x8*)&Ws[(wn2 + j * 16 + lrow) * 40 + quad * 8];
        #pragma unroll
        for (int i = 0; i < 4; i++)
            #pragma unroll
            for (int j = 0; j < 4; j++)
                acc[i][j] = __builtin_amdgcn_mfma_f32_16x16x32_bf16(af[i], bf[j], acc[i][j], 0, 0, 0);
    }

    #pragma unroll
    for (int i = 0; i < 4; i++) {
        #pragma unroll
        for (int j = 0; j < 4; j++) {
            #pragma unroll
            for (int r = 0; r < 4; r++) {
                int row = m0 + wm + i * 16 + quad * 4 + r;
                int col = n0 + wn2 + j * 16 + lrow;
                float v = acc[i][j][r] * alpha;
                if (BIAS) v += bias[col];
                if (RELU) v = fmaxf(v, 0.f);
                long long idx = cOff + (long long)row * ldc + col;
                if (OUTBF16) ((unsigned short*)Cv)[idx] = f2bf(v);
                else         ((float*)Cv)[idx] = v;
            }
        }
    }
}

// ---------------------------------------------------------------------------
__global__ void cvt_k(const float* __restrict__ in, unsigned short* __restrict__ out, int n)
{
    int i = blockIdx.x * 256 + threadIdx.x;
    int stride = gridDim.x * 256;
    for (; i < n; i += stride) out[i] = f2bf(in[i]);
}

// ---------------------------------------------------------------------------
// GARCH: per-batch variance + 511-step scalar recurrence. 1 block, lane = batch.
// ---------------------------------------------------------------------------
__global__ __launch_bounds__(64) void garch_k(
    const float* __restrict__ xe, const float* __restrict__ omega,
    const float* __restrict__ alpha, const float* __restrict__ beta,
    float* __restrict__ vol)
{
    int b = threadIdx.x;
    float sm = 0.f, sq = 0.f;
    for (int t2 = 0; t2 < TT; t2++) {
        float r = xe[((long long)b * TT + t2) * EE + 5];
        sm += r; sq += r * r;
    }
    float mean = sm / 512.f;
    float var = (sq - 512.f * mean * mean) / 511.f;
    float h = var + 1e-6f;
    float om = log1pf(expf(omega[0]));
    float al = 0.2f / (1.f + expf(-alpha[0]));
    float be = 0.8f / (1.f + expf(-beta[0]));
    for (int t2 = 0; t2 < TT - 1; t2++) {
        float r = xe[((long long)b * TT + t2) * EE + 5];
        h = om + al * r * r + be * h;
    }
    vol[b] = sqrtf(h);
}

// ---------------------------------------------------------------------------
// Persistent LSTM v3 — LDS-staged h, minimal coherent traffic.
//
// Round-1 post-mortem: agent-scope loads bypass L1+L2; per-thread scattered
// h loads with dl-duplication = 86 MB/step coherent traffic -> 34us/step
// pure-BW-bound (FETCH 44 GB, VALUBusy 5.6%).
//
// v3: stage the FULL h (512x64 f32 = 128 KB) into LDS ONCE per block per
// step via 64 coalesced __hip_atomic_load dwords/thread (proven-correct
// coherence path from round 1), then all 8 waves read from LDS.
// Coherent traffic: 128 KB x 256 blocks = 32 MB/step (2.7x cut, and no
// 4B-granule scatter). w_hh stays in L1 (16 KB/block, plain cached loads;
// VMEM issue hides under VALU). Everything else (barrier, fin math,
// h write-through) unchanged from the passing round-1 kernel.
//
// Geometry: 256 blocks x 512 threads (8 waves). wave = dl*4+kq.
// LDS: 128 KB h + 8 KB partials = 136 KB -> 1 block/CU, grid 256 = CUs,
// co-resident by capacity; barrier has a tries-breakout so it can never
// wedge the queue.
// ---------------------------------------------------------------------------
__global__ __launch_bounds__(512, 2) void lstm_persist3_k(
    const float* __restrict__ xe, const float* __restrict__ w_hh,
    const float* __restrict__ w_ih, const float* __restrict__ b_ih,
    const float* __restrict__ b_hh,
    float* __restrict__ h0, float* __restrict__ h1,
    float* __restrict__ xT,
    unsigned* __restrict__ root, unsigned* __restrict__ grp)
{
    __shared__ float hs[512 * 64];     // staged h[k][b], 128 KB
    __shared__ float part[8][4][64];   // per-wave partials, 8 KB

    int blk = blockIdx.x;
    int tid = threadIdx.x;
    int wave = tid >> 6, lane = tid & 63;
    int dl = wave >> 2;      // 0..1
    int kq = wave & 3;       // 0..3
    int d = blk * 2 + dl;    // 0..511

    const float* wrow = w_hh + (long long)d * 512 + kq * 128;

    bool fin = (kq == 0);
    float wi[4][6], bs[4];
    if (fin) {
        #pragma unroll
        for (int g = 0; g < 4; g++) {
            int row = g * 512 + d;
            #pragma unroll
            for (int e = 0; e < 6; e++) wi[g][e] = w_ih[row * 6 + e];
            bs[g] = b_ih[row] + b_hh[row];
        }
    }
    float c = 0.f;

    for (int t = 0; t < TT; t++) {
        const float* hin  = (t & 1) ? h1 : h0;
        float*       hout = (t & 1) ? h0 : h1;

        // ---- Stage full h into LDS (coherent coalesced loads) ----
        // flat dword i = j*512 + tid : global hin[i] -> hs[i]
        float hv[64];
        #pragma unroll
        for (int j = 0; j < 64; j++)
            hv[j] = __hip_atomic_load(&hin[j * 512 + tid], __ATOMIC_RELAXED,
                                      __HIP_MEMORY_SCOPE_AGENT);
        // xe(t) prefetch for finalize waves (normal cached loads, hides here)
        float x0 = 0.f, x1 = 0.f, x2 = 0.f, x3 = 0.f, x4 = 0.f, x5 = 0.f;
        if (fin) {
            const float* xr = xe + ((long long)lane * TT + t) * EE;
            x0 = xr[0]; x1 = xr[1]; x2 = xr[2];
            x3 = xr[3]; x4 = xr[4]; x5 = xr[5];
        }
        #pragma unroll
        for (int j = 0; j < 64; j++)
            hs[j * 512 + tid] = hv[j];
        __syncthreads();   // staged h visible to all waves

        // ---- Gate dot-products from LDS (w_hh from L1) ----
        const float* hq = &hs[kq * 128 * 64 + lane];
        float a0 = 0.f, a1 = 0.f, a2 = 0.f, a3 = 0.f;
        #pragma unroll 16
        for (int k = 0; k < 128; k++) {
            float hvv = hq[k * 64];
            a0 += hvv * wrow[k];
            a1 += hvv * wrow[262144 + k];
            a2 += hvv * wrow[524288 + k];
            a3 += hvv * wrow[786432 + k];
        }

        part[wave][0][lane] = a0; part[wave][1][lane] = a1;
        part[wave][2][lane] = a2; part[wave][3][lane] = a3;
        __syncthreads();   // sync1: partials visible (also: done reading hs)

        if (fin) {
            int w0 = dl * 4;
            float s0 = part[w0][0][lane] + part[w0 + 1][0][lane]
                     + part[w0 + 2][0][lane] + part[w0 + 3][0][lane];
            float s1 = part[w0][1][lane] + part[w0 + 1][1][lane]
                     + part[w0 + 2][1][lane] + part[w0 + 3][1][lane];
            float s2 = part[w0][2][lane] + part[w0 + 1][2][lane]
                     + part[w0 + 2][2][lane] + part[w0 + 3][2][lane];
            float s3 = part[w0][3][lane] + part[w0 + 1][3][lane]
                     + part[w0 + 2][3][lane] + part[w0 + 3][3][lane];
            float pi = s0 + x0*wi[0][0] + x1*wi[0][1] + x2*wi[0][2]
                          + x3*wi[0][3] + x4*wi[0][4] + x5*wi[0][5] + bs[0];
            float pf = s1 + x0*wi[1][0] + x1*wi[1][1] + x2*wi[1][2]
                          + x3*wi[1][3] + x4*wi[1][4] + x5*wi[1][5] + bs[1];
            float pg = s2 + x0*wi[2][0] + x1*wi[2][1] + x2*wi[2][2]
                          + x3*wi[2][3] + x4*wi[2][4] + x5*wi[2][5] + bs[2];
            float po = s3 + x0*wi[3][0] + x1*wi[3][1] + x2*wi[3][2]
                          + x3*wi[3][3] + x4*wi[3][4] + x5*wi[3][5] + bs[3];
            float ig = 1.f / (1.f + __expf(-pi));
            float fg = 1.f / (1.f + __expf(-pf));
            float gg = tanhf(pg);
            float og = 1.f / (1.f + __expf(-po));
            c = fg * c + ig * gg;
            float hn = og * tanhf(c);
            __hip_atomic_store(&hout[d * 64 + lane], hn, __ATOMIC_RELAXED,
                               __HIP_MEMORY_SCOPE_AGENT);
            xT[((long long)t * 512 + d) * 64 + lane] = hn;
            // h stores must be at the coherence point before arrival.
            asm volatile("s_waitcnt vmcnt(0)" ::: "memory");
        }
        __syncthreads();   // sync2: both fin waves' stores landed

        if (t < TT - 1) {
            if (tid == 0) {
                int g = blk >> 4;
                unsigned p = __hip_atomic_fetch_add(&grp[g * 512 + t], 1u,
                                 __ATOMIC_RELAXED, __HIP_MEMORY_SCOPE_AGENT);
                if (p == 15u) {
                    __hip_atomic_fetch_add(&root[t], 1u,
                        __ATOMIC_RELAXED, __HIP_MEMORY_SCOPE_AGENT);
                }
                unsigned tries = 0;
                while (__hip_atomic_load(&root[t], __ATOMIC_RELAXED,
                                         __HIP_MEMORY_SCOPE_AGENT) < 16u) {
                    __builtin_amdgcn_s_sleep(2);
                    if (++tries > 100000000u) break;   // fail loudly, never wedge
                }
            }
            __syncthreads();   // sync3: release whole block into step t+1
        }
    }
}

// ---------------------------------------------------------------------------
// Transpose xT[t][d][b] -> XB[b][t][d] bf16
// ---------------------------------------------------------------------------
__global__ __launch_bounds__(256) void transpose_k(
    const float* __restrict__ xT, unsigned short* __restrict__ XB_)
{
    __shared__ float tile[64][65];
    int dc = blockIdx.x, t = blockIdx.y;
    int tid = threadIdx.x;
    int bcol = tid & 63, grp = tid >> 6;
    #pragma unroll
    for (int j = 0; j < 16; j++) {
        int i = grp * 16 + j;
        tile[i][bcol] = xT[((long long)t * 512 + dc * 64 + i) * 64 + bcol];
    }
    __syncthreads();
    #pragma unroll
    for (int j = 0; j < 16; j++) {
        int brow = grp * 16 + j;
        float v = tile[bcol][brow];
        long long idx = ((long long)brow * TT + t) * DD + dc * 64 + bcol;
        XB_[idx] = f2bf(v);
    }
}

// ---------------------------------------------------------------------------
// Softmax over last dim (512), in-place on bf16 scores. One wave per row.
// ---------------------------------------------------------------------------
__global__ __launch_bounds__(256) void softmax_k(unsigned short* __restrict__ S)
{
    long long row = (long long)blockIdx.x * 4 + (threadIdx.x >> 6);
    int lane = threadIdx.x & 63;
    unsigned short* p = S + row * 512 + lane * 8;
    uint4 raw = *(const uint4*)p;
    unsigned short* u = (unsigned short*)&raw;
    float v[8];
    float m = -1e30f;
    #pragma unroll
    for (int j = 0; j < 8; j++) { v[j] = bf2f(u[j]); m = fmaxf(m, v[j]); }
    #pragma unroll
    for (int off = 1; off < 64; off <<= 1) m = fmaxf(m, __shfl_xor(m, off));
    float s = 0.f;
    #pragma unroll
    for (int j = 0; j < 8; j++) { v[j] = __expf(v[j] - m); s += v[j]; }
    #pragma unroll
    for (int off = 1; off < 64; off <<= 1) s += __shfl_xor(s, off);
    float inv = 1.f / s;
    unsigned int pk[4];
    #pragma unroll
    for (int j = 0; j < 4; j++)
        pk[j] = (unsigned int)f2bf(v[2 * j] * inv) | ((unsigned int)f2bf(v[2 * j + 1] * inv) << 16);
    *(uint4*)p = make_uint4(pk[0], pk[1], pk[2], pk[3]);
}

// ---------------------------------------------------------------------------
// Residual + LayerNorm: XB = LN(XB + Y)*g + b  (bf16 residual stream).
// ---------------------------------------------------------------------------
__global__ __launch_bounds__(256) void ln_k(
    unsigned short* XB_, const float* __restrict__ Y_,
    const float* __restrict__ g, const float* __restrict__ b2)
{
    long long row = (long long)blockIdx.x * 4 + (threadIdx.x >> 6);
    int lane = threadIdx.x & 63;
    long long base = row * 512 + lane * 8;
    float s[8];
    {
        uint4 xr = *(const uint4*)&XB_[base];
        const unsigned short* xu = (const unsigned short*)&xr;
        float4 y0 = *(const float4*)&Y_[base];
        float4 y1 = *(const float4*)&Y_[base + 4];
        s[0] = bf2f(xu[0]) + y0.x; s[1] = bf2f(xu[1]) + y0.y;
        s[2] = bf2f(xu[2]) + y0.z; s[3] = bf2f(xu[3]) + y0.w;
        s[4] = bf2f(xu[4]) + y1.x; s[5] = bf2f(xu[5]) + y1.y;
        s[6] = bf2f(xu[6]) + y1.z; s[7] = bf2f(xu[7]) + y1.w;
    }
    float sm = 0.f, sq = 0.f;
    #pragma unroll
    for (int j = 0; j < 8; j++) { sm += s[j]; sq += s[j] * s[j]; }
    #pragma unroll
    for (int off = 1; off < 64; off <<= 1) {
        sm += __shfl_xor(sm, off);
        sq += __shfl_xor(sq, off);
    }
    float mean = sm * (1.f / 512.f);
    float var = sq * (1.f / 512.f) - mean * mean;
    float rstd = rsqrtf(var + 1e-5f);
    int col = lane * 8;
    float o[8];
    #pragma unroll
    for (int j = 0; j < 8; j++) o[j] = (s[j] - mean) * rstd * g[col + j] + b2[col + j];
    unsigned int pk[4];
    #pragma unroll
    for (int j = 0; j < 4; j++)
        pk[j] = (unsigned int)f2bf(o[2 * j]) | ((unsigned int)f2bf(o[2 * j + 1]) << 16);
    *(uint4*)&XB_[base] = make_uint4(pk[0], pk[1], pk[2], pk[3]);
}

// ---------------------------------------------------------------------------
// Heads: garch_base + gate * ai_residual. One block per batch.
// ---------------------------------------------------------------------------
__global__ __launch_bounds__(128) void head_k(
    const unsigned short* __restrict__ XB_, const float* __restrict__ xe,
    const float* __restrict__ vol,
    const float* __restrict__ rh_w, const float* __restrict__ rh_b,
    const float* __restrict__ g1_w, const float* __restrict__ g1_b,
    const float* __restrict__ g2_w, const float* __restrict__ g2_b,
    const float* __restrict__ gp_w, const float* __restrict__ gp_b,
    float* __restrict__ out)
{
    int b = blockIdx.x, t = threadIdx.x;
    __shared__ float xl[512];
    __shared__ float hid[256];
    for (int j = t; j < 512; j += 128)
        xl[j] = bf2f(XB_[((long long)b * TT + (TT - 1)) * DD + j]);
    float gin[7];
    #pragma unroll
    for (int e = 0; e < 6; e++) gin[e] = xe[((long long)b * TT + (TT - 1)) * EE + e];
    gin[6] = vol[b];
    for (int j = t; j < 256; j += 128) {
        float s = g1_b[j];
        #pragma unroll
        for (int e = 0; e < 7; e++) s += g1_w[j * 7 + e] * gin[e];
        hid[j] = fmaxf(s, 0.f);
    }
    __syncthreads();
    for (int p = t; p < 96; p += 128) {
        float ai = rh_b[p];
        for (int j = 0; j < 512; j++) ai += xl[j] * rh_w[p * 512 + j];
        float gs = g2_b[p];
        for (int j = 0; j < 256; j++) gs += hid[j] * g2_w[p * 256 + j];
        float gate = 1.f / (1.f + expf(-gs));
        out[b * PP + p] = vol[b] * gp_w[p] + gp_b[p] + gate * ai;
    }
}

// ---------------------------------------------------------------------------
// Launch.  Workspace layout (bytes, total ~147.2 MB):
//   XB   bf16 residual  @ 0           (33554432)
//   Y    fp32 branch    @ 33554432    (67108864)   [aliases LSTM xT]
//   CH   chunk region   @ 100663296   (33554432)
//        QKVc @ +0 | SCc @ +12582912 | CTXc @ +29360128 ; HIDc @ +0 [FFN]
//   WB   bf16 weights   @ 134217728   (12582912)
//   HT0/HT1             @ 146800640   (2 x 131072)
//   BAR  barrier slots  @ 147062784   (34816: root 512 u32, grp 16x512 u32)
//   VOL                 @ 147193856   (256)
// ---------------------------------------------------------------------------
extern "C" void kernel_launch(void* const* d_in, const int* in_sizes, int n_in,
                              void* d_out, int out_size, void* d_ws, size_t ws_size,
                              hipStream_t stream)
{
    const float* x_enc      = (const float*)d_in[0];
    const float* omega      = (const float*)d_in[4];
    const float* alpha      = (const float*)d_in[5];
    const float* beta       = (const float*)d_in[6];
    const float* gp_w       = (const float*)d_in[7];
    const float* gp_b       = (const float*)d_in[8];
    const float* w_ih       = (const float*)d_in[9];
    const float* w_hh       = (const float*)d_in[10];
    const float* b_ih       = (const float*)d_in[11];
    const float* b_hh       = (const float*)d_in[12];
    const float* attn_in_w  = (const float*)d_in[13];
    const float* attn_in_b  = (const float*)d_in[14];
    const float* attn_out_w = (const float*)d_in[15];
    const float* attn_out_b = (const float*)d_in[16];
    const float* ln1_g      = (const float*)d_in[17];
    const float* ln1_b      = (const float*)d_in[18];
    const float* ffn_w1     = (const float*)d_in[19];
    const float* ffn_b1     = (const float*)d_in[20];
    const float* ffn_w2     = (const float*)d_in[21];
    const float* ffn_b2     = (const float*)d_in[22];
    const float* ln2_g      = (const float*)d_in[23];
    const float* ln2_b      = (const float*)d_in[24];
    const float* rh_w       = (const float*)d_in[25];
    const float* rh_b       = (const float*)d_in[26];
    const float* g1_w       = (const float*)d_in[27];
    const float* g1_b       = (const float*)d_in[28];
    const float* g2_w       = (const float*)d_in[29];
    const float* g2_b       = (const float*)d_in[30];

    char* ws = (char*)d_ws;
    unsigned short* XB   = (unsigned short*)(ws + 0);
    float*          Y    = (float*)(ws + 33554432LL);
    float*          XT   = Y;
    unsigned short* QKVc = (unsigned short*)(ws + 100663296LL);
    unsigned short* SCc  = (unsigned short*)(ws + 113246208LL);
    unsigned short* CTXc = (unsigned short*)(ws + 130023424LL);
    unsigned short* HIDc = (unsigned short*)(ws + 100663296LL);
    unsigned short* WATI = (unsigned short*)(ws + 134217728LL);
    unsigned short* WATO = WATI + 1572864;
    unsigned short* WF1  = WATI + 2097152;
    unsigned short* WF2  = WATI + 4194304;
    float*          HT0  = (float*)(ws + 146800640LL);
    float*          HT1  = (float*)(ws + 146931712LL);
    unsigned*       ROOT = (unsigned*)(ws + 147062784LL);
    unsigned*       GRP  = ROOT + 512;
    float*          VOL  = (float*)(ws + 147193856LL);

    hipMemsetAsync(HT0, 0, 131072, stream);
    hipMemsetAsync(ROOT, 0, 34816, stream);

    cvt_k<<<2048, 256, 0, stream>>>(attn_in_w,  WATI, 1572864);
    cvt_k<<<1024, 256, 0, stream>>>(attn_out_w, WATO, 524288);
    cvt_k<<<2048, 256, 0, stream>>>(ffn_w1,     WF1,  2097152);
    cvt_k<<<2048, 256, 0, stream>>>(ffn_w2,     WF2,  2097152);

    garch_k<<<1, 64, 0, stream>>>(x_enc, omega, alpha, beta, VOL);

    // Persistent LSTM v3: one launch, LDS-staged h, minimal coherent traffic.
    lstm_persist3_k<<<256, 512, 0, stream>>>(x_enc, w_hh, w_ih, b_ih, b_hh,
                                             HT0, HT1, XT, ROOT, GRP);

    transpose_k<<<dim3(8, 512, 1), 256, 0, stream>>>(XT, XB);

    for (int l = 0; l < 2; l++) {
        // Attention, chunked over batches: 8 chunks x 8 batches (4096 rows)
        for (int c = 0; c < 8; c++) {
            long long rowOff = (long long)c * 8 * 512;
            gemm_bt<false, true, false, true><<<dim3(32, 12, 1), 256, 0, stream>>>(
                XB + rowOff * 512, 512, 0, 0,
                WATI + l * 786432, 512, 0, 0, attn_in_b + l * 1536,
                QKVc, 1536, 0, 0, 512, 1, 1.0f);
            gemm_bt<false, false, false, true><<<dim3(4, 4, 32), 256, 0, stream>>>(
                QKVc, 1536, 786432LL, 128LL, QKVc + 512, 1536, 786432LL, 128LL, nullptr,
                SCc, 512, 1048576LL, 262144LL, 128, 4, 0.088388347648318447f);
            softmax_k<<<4096, 256, 0, stream>>>(SCc);
            gemm_bt<true, false, false, true><<<dim3(4, 1, 32), 256, 0, stream>>>(
                SCc, 512, 1048576LL, 262144LL, QKVc + 1024, 1536, 786432LL, 128LL, nullptr,
                CTXc, 512, 262144LL, 128LL, 512, 4, 1.0f);
            gemm_bt<false, true, false, false><<<dim3(32, 4, 1), 256, 0, stream>>>(
                CTXc, 512, 0, 0, WATO + l * 262144, 512, 0, 0, attn_out_b + l * 512,
                Y + rowOff * 512, 512, 0, 0, 512, 1, 1.0f);
        }
        ln_k<<<8192, 256, 0, stream>>>(XB, Y, ln1_g + l * 512, ln1_b + l * 512);

        // FFN, chunked over rows: 4 chunks x 8192 rows
        for (int mc = 0; mc < 4; mc++) {
            long long rowOff = (long long)mc * 8192;
            gemm_bt<false, true, true, true><<<dim3(64, 16, 1), 256, 0, stream>>>(
                XB + rowOff * 512, 512, 0, 0,
                WF1 + l * 1048576, 512, 0, 0, ffn_b1 + l * 2048,
                HIDc, 2048, 0, 0, 512, 1, 1.0f);
            gemm_bt<false, true, false, false><<<dim3(64, 4, 1), 256, 0, stream>>>(
                HIDc, 2048, 0, 0, WF2 + l * 1048576, 2048, 0, 0, ffn_b2 + l * 512,
                Y + rowOff * 512, 512, 0, 0, 2048, 1, 1.0f);
        }
        ln_k<<<8192, 256, 0, stream>>>(XB, Y, ln2_g + l * 512, ln2_b + l * 512);
    }

    head_k<<<64, 128, 0, stream>>>(XB, x_enc, VOL, rh_w, rh_b,
                                   g1_w, g1_b, g2_w, g2_b, gp_w, gp_b,
                                   (float*)d_out);
}